// Round 5
// baseline (164.877 us; speedup 1.0000x reference)
//
#include <hip/hip_runtime.h>
#include <math.h>

#define NN 200000
#define DD 64
#define BB 4096
#define KK 128
#define WW 20
#define HH 128
#define TPB 512
#define RPB 4    // targets per block; 8 waves = 2 waves per target

#define INV2PI 0.15915494309189535f

__device__ __forceinline__ float fast_rcp(float x) { return __builtin_amdgcn_rcpf(x); }
__device__ __forceinline__ float fast_rsq(float x) { return __builtin_amdgcn_rsqf(x); }

// Fully-fused pipeline; round 4/5 attacks the invariant VALU work:
//   - all cos paths are bounded v_mul+v_cos (__builtin_amdgcn_cosf), no OCML
//     argument-reduction expansion.
//   - part A fully unrolled so the compiler pipelines the 5 s_loads/d.
//   - GEMM: 2 h's x 2 rows per thread -> each tile b128 broadcast feeds 8 FMAs.
//   - hist tap-split over waves 4-7 (2 threads/col x 10 taps) halves the
//     barrier-A straggler; partials combined via hp after barrier C.
// 1024 blocks x 512 threads, 4 targets/block, 6 block barriers.
__global__ __launch_bounds__(512, 8) void fused(
    const float* __restrict__ adj_time, const float* __restrict__ gc,
    const float* __restrict__ cur_time, const float* __restrict__ neigh_mask,
    const float* __restrict__ hist_feat, const float* __restrict__ hist_time,
    const float* __restrict__ t2v_w, const float* __restrict__ t2v_b,
    const float* __restrict__ node_w, const float* __restrict__ node_b,
    const float* __restrict__ att_w, const float* __restrict__ att_b,
    const float* __restrict__ weight,
    const int* __restrict__ targets, const int* __restrict__ neigh_idx,
    float* __restrict__ out)
{
    const int b0   = blockIdx.x * RPB;
    const int tid  = threadIdx.x;
    const int lane = tid & 63;
    const int wv   = tid >> 6;          // wave id 0..7

    __shared__ float4 dtg[RPB * KK];    // {dt, g, wk, -}; reused as partials  8 KB
    __shared__ float  stL[RPB];         // target att-dot per row
    __shared__ float  p3p[RPB][DD];     // phase-3 odd-wave partials           1 KB
    __shared__ float  tile[RPB * 256];  // feat4 rows                          4 KB
    __shared__ float4 hp[128];          // hist tap-half-1 partials            2 KB

    const float t = cur_time[0];

    // ---- gathers: one slot per thread (slot = r*128 + k = tid) ----
    const int   slot = tid;
    const int   idx  = neigh_idx[b0 * KK + slot];
    const float m    = neigh_mask[b0 * KK + slot];
    const float at   = adj_time[idx];
    const float g    = gc[idx];
    const float dt   = fabsf(t - at);
    const float ts   = fast_rcp(2.0f * __logf(2.71828182845904523536f + (t - at)));
    dtg[slot] = make_float4(dt, g, 0.f, 0.f);

    // ---- history aggregation, waves 4-7, tap-split (2 threads/column) ----
    if (tid >= 256) {
        const int i   = tid - 256;       // 0..255
        const int col = i >> 1;          // 0..127
        const int th  = i & 1;           // tap half: 0 -> taps 0-9, 1 -> 10-19
        const int r   = col >> 5;        // target row 0..3
        const int c4  = col & 31;        // float4 column
        const float*  ht = hist_time + (size_t)(b0 + r) * WW + th * 10;
        const float4* hf = (const float4*)(hist_feat + (size_t)(b0 + r) * WW * 128)
                         + c4 + th * 10 * 32;
        float4 s4 = make_float4(0.f, 0.f, 0.f, 0.f);
#pragma unroll
        for (int w = 0; w < 10; ++w) {
            float  hw = fast_rcp(2.0f * (1.0f + (t - ht[w])));
            float4 v  = hf[w * 32];
            s4.x = fmaf(hw, v.x, s4.x);
            s4.y = fmaf(hw, v.y, s4.y);
            s4.z = fmaf(hw, v.z, s4.z);
            s4.w = fmaf(hw, v.w, s4.w);
        }
        if (th == 0) *(float4*)(tile + r * 256 + c4 * 4) = s4;
        else         hp[col] = s4;
    }

    // ---- target encoding, wave wv -> target wv (waves 0-3) ----
    if (wv < RPB) {
        int   tg  = targets[b0 + wv];
        float dtT = fabsf(t - adj_time[tg]);
        float gT  = gc[tg];
        float ph  = fmaf(t2v_w[lane], dtT, t2v_b[lane]);
        float cv  = __builtin_amdgcn_cosf(ph * INV2PI);   // cos(ph) radians
        float tv_ = (lane == 0) ? ph : cv;
        float f   = fmaxf(tv_ + fmaf(gT, node_w[lane], node_b[lane]), 0.f);
        float ss  = f * f;
#pragma unroll
        for (int off = 32; off; off >>= 1) ss += __shfl_xor(ss, off, 64);
        float invn = fast_rsq(fmaxf(ss, 1e-24f));
        float tfn  = f * invn;
        float sdt  = tfn * att_w[lane];
#pragma unroll
        for (int off = 32; off; off >>= 1) sdt += __shfl_xor(sdt, off, 64);
        if (lane == 0) stL[wv] = sdt;
        tile[wv * 256 + 128 + lane] = tfn;
    }

    // ---- part A: 64-dim in-lane norm+att from registers (no LDS deps) ----
    float s2, sd;
    {
        {   // d = 0: linear channel (no cos)
            float ph = fmaf(t2v_w[0], dt, t2v_b[0]);
            float f  = fmaxf(ph + fmaf(g, node_w[0], node_b[0]), 0.f);
            s2 = f * f;
            sd = f * att_w[64];
        }
#pragma unroll
        for (int d = 1; d < 64; ++d) {
            float ph = fmaf(t2v_w[d], dt, t2v_b[d]);
            float cv = __builtin_amdgcn_cosf(ph * INV2PI);   // v_mul + v_cos only
            float f  = fmaxf(cv + fmaf(g, node_w[d], node_b[d]), 0.f);
            s2 = fmaf(f, f, s2);
            sd = fmaf(f, att_w[64 + d], sd);
        }
    }
    __syncthreads();   // A: stL, dtg.xy, hist tile/hp writes ready

    // ---- part B: finish score, write wk ----
    {
        float invn = fast_rsq(fmaxf(s2, 1e-24f));
        float sc   = ts + stL[slot >> 7] + sd * invn + att_b[0];
        sc = (sc > 0.f) ? sc : 0.01f * sc;          // leaky_relu(0.01)
        dtg[slot].z = sc * m * invn;                // packed wk
    }
    __syncthreads();   // C: wk ready

    // ---- hist tap-half combine (threads 0-127), overlapped with phase 3 ----
    if (tid < 128) {
        int r = tid >> 5, c4 = tid & 31;
        float4* tp = (float4*)(tile + r * 256 + c4 * 4);
        float4 a = *tp, b = hp[tid];
        *tp = make_float4(a.x + b.x, a.y + b.y, a.z + b.z, a.w + b.w);
    }

    // ---- phase 3: wave pair (2r, 2r+1) owns target r; lane = dim ----
    const int r3   = wv >> 1;
    const int half = wv & 1;
    float acc3 = 0.f;
    {
        float scn = (lane == 0) ? 1.f : INV2PI;     // lane 0 = linear channel
        float pw  = t2v_w[lane] * scn;
        float pb  = t2v_b[lane] * scn;
        float nw  = node_w[lane];
        float nb2 = node_b[lane];
        const int base = r3 * KK + half * 64;
#pragma unroll 4
        for (int k = 0; k < 64; ++k) {
            float4 dgw = dtg[base + k];             // uniform addr -> broadcast b128
            float  ph  = fmaf(pw, dgw.x, pb);
            float  cv  = __builtin_amdgcn_cosf(ph); // v_cos: cos(2*pi*ph)
            float  tv_ = lane ? cv : ph;
            float  f   = fmaxf(tv_ + fmaf(dgw.y, nw, nb2), 0.f);
            acc3 = fmaf(dgw.z, f, acc3);
        }
    }
    if (half) p3p[r3][lane] = acc3;
    __syncthreads();   // D: odd-wave partials ready
    if (!half) tile[r3 * 256 + 192 + lane] = acc3 + p3p[r3][lane];
    __syncthreads();   // E: tile complete; dtg dead

    // ---- GEMM: thread = (h2, sq, rh); 2 h x 2 rows in registers ----
    const int h2 = tid & 63;            // h and h+64
    const int sq = (tid >> 6) & 3;      // j-quarter 0..3
    const int rh = tid >> 8;            // row pair 0..1
    const float4* wA = (const float4*)weight + (h2     ) * 64 + sq * 16;
    const float4* wB = (const float4*)weight + (h2 + 64) * 64 + sq * 16;
    const float*  t0 = tile + (2 * rh    ) * 256 + sq * 64;
    const float*  t1 = tile + (2 * rh + 1) * 256 + sq * 64;
    float a00 = 0.f, a01 = 0.f, a10 = 0.f, a11 = 0.f;   // [row][h]
#pragma unroll 4
    for (int i = 0; i < 16; ++i) {
        float4 wa = wA[i];
        float4 wb = wB[i];
        float4 f0 = *(const float4*)(t0 + i * 4);   // uniform broadcasts
        float4 f1 = *(const float4*)(t1 + i * 4);
        a00 += wa.x * f0.x + wa.y * f0.y + wa.z * f0.z + wa.w * f0.w;
        a01 += wb.x * f0.x + wb.y * f0.y + wb.z * f0.z + wb.w * f0.w;
        a10 += wa.x * f1.x + wa.y * f1.y + wa.z * f1.z + wa.w * f1.w;
        a11 += wb.x * f1.x + wb.y * f1.y + wb.z * f1.z + wb.w * f1.w;
    }

    // ---- combine 4 sq-partials per (row, h) via dead dtg buffer ----
    float* prow = (float*)dtg;                      // 2048 floats
    prow[((2 * rh    ) * 4 + sq) * 128 + h2     ] = a00;
    prow[((2 * rh    ) * 4 + sq) * 128 + h2 + 64] = a01;
    prow[((2 * rh + 1) * 4 + sq) * 128 + h2     ] = a10;
    prow[((2 * rh + 1) * 4 + sq) * 128 + h2 + 64] = a11;
    __syncthreads();   // F
    {
        const int r2 = tid >> 7;
        const int h  = tid & 127;
        float s = prow[(r2 * 4 + 0) * 128 + h] + prow[(r2 * 4 + 1) * 128 + h]
                + prow[(r2 * 4 + 2) * 128 + h] + prow[(r2 * 4 + 3) * 128 + h];
        out[(size_t)(b0 + r2) * 128 + h] = fmaxf(s, 0.f);
    }
}

extern "C" void kernel_launch(void* const* d_in, const int* in_sizes, int n_in,
                              void* d_out, int out_size, void* d_ws, size_t ws_size,
                              hipStream_t stream) {
    const float* adj_time  = (const float*)d_in[0];
    const float* gc        = (const float*)d_in[1];
    const float* cur_time  = (const float*)d_in[2];
    const float* neigh_mask= (const float*)d_in[3];
    const float* hist_feat = (const float*)d_in[4];
    const float* hist_time = (const float*)d_in[5];
    const float* t2v_w     = (const float*)d_in[6];
    const float* t2v_b     = (const float*)d_in[7];
    const float* node_w    = (const float*)d_in[8];
    const float* node_b    = (const float*)d_in[9];
    const float* att_w     = (const float*)d_in[10];
    const float* att_b     = (const float*)d_in[11];
    const float* weight    = (const float*)d_in[12];
    const int*   targets   = (const int*)d_in[13];
    const int*   neigh_idx = (const int*)d_in[14];

    float* out = (float*)d_out;

    fused<<<BB / RPB, TPB, 0, stream>>>(adj_time, gc, cur_time, neigh_mask,
                                        hist_feat, hist_time, t2v_w, t2v_b,
                                        node_w, node_b, att_w, att_b, weight,
                                        targets, neigh_idx, out);
}

// Round 6
// 138.413 us; speedup vs baseline: 1.1912x; 1.1912x over previous
//
#include <hip/hip_runtime.h>
#include <math.h>

#define NN 200000
#define DD 64
#define BB 4096
#define KK 128
#define WW 20
#define HH 128
#define TPB 512
#define RPB 4    // targets per block; 8 waves = 2 waves per target

#define INV2PI 0.15915494309189535f

__device__ __forceinline__ float fast_rcp(float x) { return __builtin_amdgcn_rcpf(x); }
__device__ __forceinline__ float fast_rsq(float x) { return __builtin_amdgcn_rsqf(x); }

// Round 6 = verified round-3 structure (42.4 us) + ONE delta: part A and the
// target encoding use the bounded v_mul+v_cos form (__builtin_amdgcn_cosf on
// revolutions) that phase 3 has used since round 1, instead of OCML __cosf.
// Everything else is verbatim round 3:
//   start : gathers (1 slot/thread) -> dtg{dt,g,-,-}; waves 6-7 run the whole
//           history aggregation; waves 0-3 target encodings -> stL + tile.
//   partA : 64-dim feature norm+att dot in-lane (unroll 4) before barrier A.
//   partB : finish score with stL, write wk -> dtg.z.
//   phase3: wave pair (2r,2r+1) owns target r; lane=dim; 64 uniform b128
//           broadcasts; partials combined via p3p.
//   GEMM  : thread=(h, j-quarter) reads W float4 straight from L2; tile rows
//           via uniform LDS broadcasts; partials combined through dead dtg.
// 1024 blocks x 512 threads, 4 targets/block, 6 block barriers.
__global__ __launch_bounds__(512, 8) void fused(
    const float* __restrict__ adj_time, const float* __restrict__ gc,
    const float* __restrict__ cur_time, const float* __restrict__ neigh_mask,
    const float* __restrict__ hist_feat, const float* __restrict__ hist_time,
    const float* __restrict__ t2v_w, const float* __restrict__ t2v_b,
    const float* __restrict__ node_w, const float* __restrict__ node_b,
    const float* __restrict__ att_w, const float* __restrict__ att_b,
    const float* __restrict__ weight,
    const int* __restrict__ targets, const int* __restrict__ neigh_idx,
    float* __restrict__ out)
{
    const int b0   = blockIdx.x * RPB;
    const int tid  = threadIdx.x;
    const int lane = tid & 63;
    const int wv   = tid >> 6;          // wave id 0..7

    __shared__ float4 dtg[RPB * KK];    // {dt, g, wk, -}; reused as partials  8 KB
    __shared__ float  stL[RPB];         // target att-dot per row
    __shared__ float  p3p[RPB][DD];     // phase-3 odd-wave partials           1 KB
    __shared__ float  tile[RPB * 256];  // feat4 rows                          4 KB

    const float t = cur_time[0];

    // ---- gathers: one slot per thread (slot = r*128 + k = tid) ----
    const int   slot = tid;
    const int   idx  = neigh_idx[b0 * KK + slot];
    const float m    = neigh_mask[b0 * KK + slot];
    const float at   = adj_time[idx];
    const float g    = gc[idx];
    const float dt   = fabsf(t - at);
    const float ts   = fast_rcp(2.0f * __logf(2.71828182845904523536f + (t - at)));
    dtg[slot] = make_float4(dt, g, 0.f, 0.f);

    // ---- history aggregation, waves 6-7, fully self-contained ----
    if (tid >= 384) {
        const int r  = (tid >> 5) & 3;   // 0..3
        const int c4 = tid & 31;         // float4 column
        const float*  ht = hist_time + (size_t)(b0 + r) * WW;
        const float4* hf = (const float4*)(hist_feat + (size_t)(b0 + r) * WW * 128) + c4;
        float4 s4 = make_float4(0.f, 0.f, 0.f, 0.f);
#pragma unroll 4
        for (int w = 0; w < WW; ++w) {
            float  hw = fast_rcp(2.0f * (1.0f + (t - ht[w])));
            float4 v  = hf[w * 32];
            s4.x = fmaf(hw, v.x, s4.x);
            s4.y = fmaf(hw, v.y, s4.y);
            s4.z = fmaf(hw, v.z, s4.z);
            s4.w = fmaf(hw, v.w, s4.w);
        }
        *(float4*)(tile + r * 256 + c4 * 4) = s4;
    }

    // ---- target encoding, wave wv -> target wv (waves 0-3) ----
    if (wv < RPB) {
        int   tg  = targets[b0 + wv];
        float dtT = fabsf(t - adj_time[tg]);
        float gT  = gc[tg];
        float ph  = fmaf(t2v_w[lane], dtT, t2v_b[lane]);
        float cv  = __builtin_amdgcn_cosf(ph * INV2PI);   // bounded v_mul+v_cos
        float tv_ = (lane == 0) ? ph : cv;
        float f   = fmaxf(tv_ + fmaf(gT, node_w[lane], node_b[lane]), 0.f);
        float ss  = f * f;
#pragma unroll
        for (int off = 32; off; off >>= 1) ss += __shfl_xor(ss, off, 64);
        float invn = fast_rsq(fmaxf(ss, 1e-24f));
        float tfn  = f * invn;
        float sdt  = tfn * att_w[lane];
#pragma unroll
        for (int off = 32; off; off >>= 1) sdt += __shfl_xor(sdt, off, 64);
        if (lane == 0) stL[wv] = sdt;
        tile[wv * 256 + 128 + lane] = tfn;
    }

    // ---- part A: 64-dim in-lane norm+att from registers (no LDS deps) ----
    float s2, sd;
    {
        {   // d = 0: linear channel (no cos)
            float ph = fmaf(t2v_w[0], dt, t2v_b[0]);
            float f  = fmaxf(ph + fmaf(g, node_w[0], node_b[0]), 0.f);
            s2 = f * f;
            sd = f * att_w[64];
        }
#pragma unroll 4
        for (int d = 1; d < 64; ++d) {
            float ph = fmaf(t2v_w[d], dt, t2v_b[d]);
            float cv = __builtin_amdgcn_cosf(ph * INV2PI);   // bounded v_mul+v_cos
            float f  = fmaxf(cv + fmaf(g, node_w[d], node_b[d]), 0.f);
            s2 = fmaf(f, f, s2);
            sd = fmaf(f, att_w[64 + d], sd);
        }
    }
    __syncthreads();   // A: stL ready (dtg.xy, hist tile writes also done)

    // ---- part B: finish score, write wk ----
    {
        float invn = fast_rsq(fmaxf(s2, 1e-24f));
        float sc   = ts + stL[slot >> 7] + sd * invn + att_b[0];
        sc = (sc > 0.f) ? sc : 0.01f * sc;          // leaky_relu(0.01)
        dtg[slot].z = sc * m * invn;                // packed wk
    }
    __syncthreads();   // C: wk ready

    // ---- phase 3: wave pair (2r, 2r+1) owns target r; lane = dim ----
    const int r3   = wv >> 1;
    const int half = wv & 1;
    float acc3 = 0.f;
    {
        float scn = (lane == 0) ? 1.f : INV2PI;     // lane 0 = linear channel
        float pw  = t2v_w[lane] * scn;
        float pb  = t2v_b[lane] * scn;
        float nw  = node_w[lane];
        float nb2 = node_b[lane];
        const int base = r3 * KK + half * 64;
#pragma unroll 4
        for (int k = 0; k < 64; ++k) {
            float4 dgw = dtg[base + k];             // uniform addr -> broadcast b128
            float  ph  = fmaf(pw, dgw.x, pb);
            float  cv  = __builtin_amdgcn_cosf(ph); // v_cos: cos(2*pi*ph)
            float  tv_ = lane ? cv : ph;
            float  f   = fmaxf(tv_ + fmaf(dgw.y, nw, nb2), 0.f);
            acc3 = fmaf(dgw.z, f, acc3);
        }
    }
    if (half) p3p[r3][lane] = acc3;
    __syncthreads();   // D: odd-wave partials ready; dtg dead after this point
    if (!half) tile[r3 * 256 + 192 + lane] = acc3 + p3p[r3][lane];
    __syncthreads();   // E: tile complete

    // ---- GEMM: thread = (h, sq); W float4 straight from L2, once/block ----
    const int h  = tid & 127;
    const int sq = tid >> 7;                        // j-quarter 0..3
    const float4* w4 = (const float4*)weight + h * 64 + sq * 16;
    const int jb = sq * 64;
    float a0 = 0.f, a1 = 0.f, a2 = 0.f, a3 = 0.f;
#pragma unroll 4
    for (int j4 = 0; j4 < 16; ++j4) {
        float4 w  = w4[j4];
        const int jo = jb + j4 * 4;
        float4 f0 = *(const float4*)(tile + 0 * 256 + jo);   // uniform broadcasts
        float4 f1 = *(const float4*)(tile + 1 * 256 + jo);
        float4 f2 = *(const float4*)(tile + 2 * 256 + jo);
        float4 f3 = *(const float4*)(tile + 3 * 256 + jo);
        a0 += w.x * f0.x + w.y * f0.y + w.z * f0.z + w.w * f0.w;
        a1 += w.x * f1.x + w.y * f1.y + w.z * f1.z + w.w * f1.w;
        a2 += w.x * f2.x + w.y * f2.y + w.z * f2.z + w.w * f2.w;
        a3 += w.x * f3.x + w.y * f3.y + w.z * f3.z + w.w * f3.w;
    }

    // ---- combine 4 sq-partials per (row, h) via dead dtg buffer ----
    float* prow = (float*)dtg;                      // 2048 floats
    prow[(0 * 4 + sq) * 128 + h] = a0;
    prow[(1 * 4 + sq) * 128 + h] = a1;
    prow[(2 * 4 + sq) * 128 + h] = a2;
    prow[(3 * 4 + sq) * 128 + h] = a3;
    __syncthreads();   // F
    {
        const int r2 = tid >> 7;
        float s = prow[(r2 * 4 + 0) * 128 + h] + prow[(r2 * 4 + 1) * 128 + h]
                + prow[(r2 * 4 + 2) * 128 + h] + prow[(r2 * 4 + 3) * 128 + h];
        out[(size_t)(b0 + r2) * 128 + h] = fmaxf(s, 0.f);
    }
}

extern "C" void kernel_launch(void* const* d_in, const int* in_sizes, int n_in,
                              void* d_out, int out_size, void* d_ws, size_t ws_size,
                              hipStream_t stream) {
    const float* adj_time  = (const float*)d_in[0];
    const float* gc        = (const float*)d_in[1];
    const float* cur_time  = (const float*)d_in[2];
    const float* neigh_mask= (const float*)d_in[3];
    const float* hist_feat = (const float*)d_in[4];
    const float* hist_time = (const float*)d_in[5];
    const float* t2v_w     = (const float*)d_in[6];
    const float* t2v_b     = (const float*)d_in[7];
    const float* node_w    = (const float*)d_in[8];
    const float* node_b    = (const float*)d_in[9];
    const float* att_w     = (const float*)d_in[10];
    const float* att_b     = (const float*)d_in[11];
    const float* weight    = (const float*)d_in[12];
    const int*   targets   = (const int*)d_in[13];
    const int*   neigh_idx = (const int*)d_in[14];

    float* out = (float*)d_out;

    fused<<<BB / RPB, TPB, 0, stream>>>(adj_time, gc, cur_time, neigh_mask,
                                        hist_feat, hist_time, t2v_w, t2v_b,
                                        node_w, node_b, att_w, att_b, weight,
                                        targets, neigh_idx, out);
}

// Round 7
// 136.472 us; speedup vs baseline: 1.2081x; 1.0142x over previous
//
#include <hip/hip_runtime.h>
#include <math.h>

#define NN 200000
#define DD 64
#define BB 4096
#define KK 128
#define WW 20
#define HH 128
#define TPB 512
#define RPB 4    // targets per block

#define INV2PI 0.15915494309189535f

__device__ __forceinline__ float fast_rcp(float x) { return __builtin_amdgcn_rcpf(x); }
__device__ __forceinline__ float fast_rsq(float x) { return __builtin_amdgcn_rsqf(x); }

// DPP cross-lane add: x + dpp_move(x). VALU-speed, no LDS pipe.
template <int CTRL>
__device__ __forceinline__ float dpp_add(float x) {
    int y = __builtin_amdgcn_update_dpp(0, __float_as_int(x), CTRL, 0xF, 0xF, true);
    return x + __int_as_float(y);
}
#define DPP_XOR1  0xB1   // quad_perm [1,0,3,2]
#define DPP_XOR2  0x4E   // quad_perm [2,3,0,1]
#define DPP_HMIRR 0x141  // row_half_mirror (j -> 7-j within 8)
#define DPP_ROR8  0x128  // row_ror:8 (j -> j+8 within row of 16)

// Round 7: register-resident core. Thread = (slot, dim-octet dg=lane>>3).
// Per-dim params (t2v/node/att, 5 x 8) live in VGPRs, loaded once. The
// score+aggregation core (old part A + part B + phase 3) runs with ZERO
// s_loads and ZERO LDS accesses in the hot loops:
//   per target r (x4), per pass (x2: slots pass*64 + wv*8 + lane&7):
//     one broadcast b128 read of dtg{dt,g,ts,m} -> 8-dim feature in-lane
//     -> s2/sd via ror8-DPP + shfl_xor(16,32) -> wk in-register
//     -> acc[i] += wk*f[i]
//   per target: slot-tree (xor1/xor2/half_mirror DPP) -> head lanes write
//   part[r][wave][dim]; combine phase sums 8 waves -> tile cols 192-255.
// Feature matrix computed ONCE (was twice); wk never touches LDS.
// Hist (waves 6-7), target-enc (waves 0-3), GEMM, output: verbatim R3.
// 1024 blocks x 512 threads, 4 barriers.
__global__ __launch_bounds__(512, 4) void fused(
    const float* __restrict__ adj_time, const float* __restrict__ gc,
    const float* __restrict__ cur_time, const float* __restrict__ neigh_mask,
    const float* __restrict__ hist_feat, const float* __restrict__ hist_time,
    const float* __restrict__ t2v_w, const float* __restrict__ t2v_b,
    const float* __restrict__ node_w, const float* __restrict__ node_b,
    const float* __restrict__ att_w, const float* __restrict__ att_b,
    const float* __restrict__ weight,
    const int* __restrict__ targets, const int* __restrict__ neigh_idx,
    float* __restrict__ out)
{
    const int b0   = blockIdx.x * RPB;
    const int tid  = threadIdx.x;
    const int lane = tid & 63;
    const int wv   = tid >> 6;          // wave id 0..7

    __shared__ float4 dtg[RPB * KK];        // {dt, g, ts, m}; reused as prow   8 KB
    __shared__ float  stL[RPB];             // target att-dot per row
    __shared__ float  part[RPB][8][DD];     // per-(target,wave) agg partials   8 KB
    __shared__ float  tile[RPB * 256];      // feat4 rows                       4 KB

    const float t = cur_time[0];

    // ---- per-lane dim-octet parameters (VGPR-resident, loaded once) ----
    const int dg = lane >> 3;           // dim octet 0..7
    const int d0 = dg * 8;
    float pw[8], pb[8], nw[8], nb[8], aw[8];
    {
        float4 a0 = *(const float4*)(t2v_w + d0),  a1 = *(const float4*)(t2v_w + d0 + 4);
        float4 b0_ = *(const float4*)(t2v_b + d0), b1 = *(const float4*)(t2v_b + d0 + 4);
        float4 c0 = *(const float4*)(node_w + d0), c1 = *(const float4*)(node_w + d0 + 4);
        float4 e0 = *(const float4*)(node_b + d0), e1 = *(const float4*)(node_b + d0 + 4);
        float4 w0 = *(const float4*)(att_w + 64 + d0), w1 = *(const float4*)(att_w + 64 + d0 + 4);
        pw[0]=a0.x*INV2PI; pw[1]=a0.y*INV2PI; pw[2]=a0.z*INV2PI; pw[3]=a0.w*INV2PI;
        pw[4]=a1.x*INV2PI; pw[5]=a1.y*INV2PI; pw[6]=a1.z*INV2PI; pw[7]=a1.w*INV2PI;
        pb[0]=b0_.x*INV2PI; pb[1]=b0_.y*INV2PI; pb[2]=b0_.z*INV2PI; pb[3]=b0_.w*INV2PI;
        pb[4]=b1.x*INV2PI; pb[5]=b1.y*INV2PI; pb[6]=b1.z*INV2PI; pb[7]=b1.w*INV2PI;
        nw[0]=c0.x; nw[1]=c0.y; nw[2]=c0.z; nw[3]=c0.w; nw[4]=c1.x; nw[5]=c1.y; nw[6]=c1.z; nw[7]=c1.w;
        nb[0]=e0.x; nb[1]=e0.y; nb[2]=e0.z; nb[3]=e0.w; nb[4]=e1.x; nb[5]=e1.y; nb[6]=e1.z; nb[7]=e1.w;
        aw[0]=w0.x; aw[1]=w0.y; aw[2]=w0.z; aw[3]=w0.w; aw[4]=w1.x; aw[5]=w1.y; aw[6]=w1.z; aw[7]=w1.w;
    }
    const float ow0 = t2v_w[0], ob0 = t2v_b[0];     // unscaled linear channel
    const float ab  = att_b[0];
    const bool  isd0 = (dg == 0);

    // ---- gathers: one slot per thread (slot = r*128 + k = tid) ----
    {
        const int   idx = neigh_idx[b0 * KK + tid];
        const float m   = neigh_mask[b0 * KK + tid];
        const float at  = adj_time[idx];
        const float g   = gc[idx];
        const float dt  = fabsf(t - at);
        const float ts  = fast_rcp(2.0f * __logf(2.71828182845904523536f + (t - at)));
        dtg[tid] = make_float4(dt, g, ts, m);
    }

    // ---- history aggregation, waves 6-7, fully self-contained (R3) ----
    if (tid >= 384) {
        const int r  = (tid >> 5) & 3;
        const int c4 = tid & 31;
        const float*  ht = hist_time + (size_t)(b0 + r) * WW;
        const float4* hf = (const float4*)(hist_feat + (size_t)(b0 + r) * WW * 128) + c4;
        float4 s4 = make_float4(0.f, 0.f, 0.f, 0.f);
#pragma unroll 4
        for (int w = 0; w < WW; ++w) {
            float  hw = fast_rcp(2.0f * (1.0f + (t - ht[w])));
            float4 v  = hf[w * 32];
            s4.x = fmaf(hw, v.x, s4.x);
            s4.y = fmaf(hw, v.y, s4.y);
            s4.z = fmaf(hw, v.z, s4.z);
            s4.w = fmaf(hw, v.w, s4.w);
        }
        *(float4*)(tile + r * 256 + c4 * 4) = s4;
    }

    // ---- target encoding, wave wv -> target wv (waves 0-3, R3/R6) ----
    if (wv < RPB) {
        int   tg  = targets[b0 + wv];
        float dtT = fabsf(t - adj_time[tg]);
        float gT  = gc[tg];
        float ph  = fmaf(t2v_w[lane], dtT, t2v_b[lane]);
        float cv  = __builtin_amdgcn_cosf(ph * INV2PI);
        float tv_ = (lane == 0) ? ph : cv;
        float f   = fmaxf(tv_ + fmaf(gT, node_w[lane], node_b[lane]), 0.f);
        float ss  = f * f;
#pragma unroll
        for (int off = 32; off; off >>= 1) ss += __shfl_xor(ss, off, 64);
        float invn = fast_rsq(fmaxf(ss, 1e-24f));
        float tfn  = f * invn;
        float sdt  = tfn * att_w[lane];
#pragma unroll
        for (int off = 32; off; off >>= 1) sdt += __shfl_xor(sdt, off, 64);
        if (lane == 0) stL[wv] = sdt;
        tile[wv * 256 + 128 + lane] = tfn;
    }
    __syncthreads();   // A: dtg, stL, hist tile cols ready

    // ---- core: score + aggregation, zero memory in the hot path ----
#pragma unroll
    for (int r = 0; r < RPB; ++r) {
        const float stv = stL[r];                   // uniform broadcast, once/target
        float acc[8] = {0.f, 0.f, 0.f, 0.f, 0.f, 0.f, 0.f, 0.f};
#pragma unroll
        for (int pass = 0; pass < 2; ++pass) {
            const float4 dgw = dtg[r * KK + pass * 64 + wv * 8 + (lane & 7)];
            const float dts = dgw.x, gs = dgw.y, tss = dgw.z, ms = dgw.w;
            float f[8], s2, sd;
            {   // i = 0 (handles the d==0 linear channel on dg==0 lanes)
                float ph  = fmaf(pw[0], dts, pb[0]);
                float cv  = __builtin_amdgcn_cosf(ph);
                float lin = fmaf(ow0, dts, ob0);
                float tv_ = isd0 ? lin : cv;
                float fv  = fmaxf(tv_ + fmaf(gs, nw[0], nb[0]), 0.f);
                f[0] = fv; s2 = fv * fv; sd = fv * aw[0];
            }
#pragma unroll
            for (int i = 1; i < 8; ++i) {
                float ph = fmaf(pw[i], dts, pb[i]);
                float cv = __builtin_amdgcn_cosf(ph);
                float fv = fmaxf(cv + fmaf(gs, nw[i], nb[i]), 0.f);
                f[i] = fv;
                s2 = fmaf(fv, fv, s2);
                sd = fmaf(fv, aw[i], sd);
            }
            // reduce s2/sd over the 8 dim-octets (stride-8 lanes)
            s2 = dpp_add<DPP_ROR8>(s2);
            s2 += __shfl_xor(s2, 16, 64);
            s2 += __shfl_xor(s2, 32, 64);
            sd = dpp_add<DPP_ROR8>(sd);
            sd += __shfl_xor(sd, 16, 64);
            sd += __shfl_xor(sd, 32, 64);
            // wk fully in-register
            float invn = fast_rsq(fmaxf(s2, 1e-24f));
            float sc   = tss + stv + sd * invn + ab;
            sc = (sc > 0.f) ? sc : 0.01f * sc;      // leaky_relu(0.01)
            float wk = sc * ms * invn;
#pragma unroll
            for (int i = 0; i < 8; ++i) acc[i] = fmaf(wk, f[i], acc[i]);
        }
        // slot-tree: sum over 8 consecutive lanes (the 8 slot positions)
#pragma unroll
        for (int i = 0; i < 8; ++i) {
            acc[i] = dpp_add<DPP_XOR1>(acc[i]);
            acc[i] = dpp_add<DPP_XOR2>(acc[i]);
            acc[i] = dpp_add<DPP_HMIRR>(acc[i]);
        }
        if ((lane & 7) == 0) {
#pragma unroll
            for (int i = 0; i < 8; ++i) part[r][wv][d0 + i] = acc[i];
        }
    }
    __syncthreads();   // D: partials ready; dtg dead

    // ---- combine: tile cols 192-255 = sum of 8 wave partials ----
    if (tid < 256) {
        const int r = tid >> 6, d = tid & 63;
        float s = 0.f;
#pragma unroll
        for (int w = 0; w < 8; ++w) s += part[r][w][d];
        tile[r * 256 + 192 + d] = s;
    }
    __syncthreads();   // E: tile complete

    // ---- GEMM: thread = (h, sq); W float4 straight from L2 (R3) ----
    const int h  = tid & 127;
    const int sq = tid >> 7;
    const float4* w4 = (const float4*)weight + h * 64 + sq * 16;
    const int jb = sq * 64;
    float a0 = 0.f, a1 = 0.f, a2 = 0.f, a3 = 0.f;
#pragma unroll 4
    for (int j4 = 0; j4 < 16; ++j4) {
        float4 w  = w4[j4];
        const int jo = jb + j4 * 4;
        float4 f0 = *(const float4*)(tile + 0 * 256 + jo);
        float4 f1 = *(const float4*)(tile + 1 * 256 + jo);
        float4 f2 = *(const float4*)(tile + 2 * 256 + jo);
        float4 f3 = *(const float4*)(tile + 3 * 256 + jo);
        a0 += w.x * f0.x + w.y * f0.y + w.z * f0.z + w.w * f0.w;
        a1 += w.x * f1.x + w.y * f1.y + w.z * f1.z + w.w * f1.w;
        a2 += w.x * f2.x + w.y * f2.y + w.z * f2.z + w.w * f2.w;
        a3 += w.x * f3.x + w.y * f3.y + w.z * f3.z + w.w * f3.w;
    }

    // ---- combine 4 sq-partials per (row, h) via dead dtg buffer ----
    float* prow = (float*)dtg;
    prow[(0 * 4 + sq) * 128 + h] = a0;
    prow[(1 * 4 + sq) * 128 + h] = a1;
    prow[(2 * 4 + sq) * 128 + h] = a2;
    prow[(3 * 4 + sq) * 128 + h] = a3;
    __syncthreads();   // F
    {
        const int r2 = tid >> 7;
        float s = prow[(r2 * 4 + 0) * 128 + h] + prow[(r2 * 4 + 1) * 128 + h]
                + prow[(r2 * 4 + 2) * 128 + h] + prow[(r2 * 4 + 3) * 128 + h];
        out[(size_t)(b0 + r2) * 128 + h] = fmaxf(s, 0.f);
    }
}

extern "C" void kernel_launch(void* const* d_in, const int* in_sizes, int n_in,
                              void* d_out, int out_size, void* d_ws, size_t ws_size,
                              hipStream_t stream) {
    const float* adj_time  = (const float*)d_in[0];
    const float* gc        = (const float*)d_in[1];
    const float* cur_time  = (const float*)d_in[2];
    const float* neigh_mask= (const float*)d_in[3];
    const float* hist_feat = (const float*)d_in[4];
    const float* hist_time = (const float*)d_in[5];
    const float* t2v_w     = (const float*)d_in[6];
    const float* t2v_b     = (const float*)d_in[7];
    const float* node_w    = (const float*)d_in[8];
    const float* node_b    = (const float*)d_in[9];
    const float* att_w     = (const float*)d_in[10];
    const float* att_b     = (const float*)d_in[11];
    const float* weight    = (const float*)d_in[12];
    const int*   targets   = (const int*)d_in[13];
    const int*   neigh_idx = (const int*)d_in[14];

    float* out = (float*)d_out;

    fused<<<BB / RPB, TPB, 0, stream>>>(adj_time, gc, cur_time, neigh_mask,
                                        hist_feat, hist_time, t2v_w, t2v_b,
                                        node_w, node_b, att_w, att_b, weight,
                                        targets, neigh_idx, out);
}